// Round 16
// baseline (852.504 us; speedup 1.0000x reference)
//
#include <hip/hip_runtime.h>
#include <cmath>

struct K32 { float k[32]; };
struct K16 { float k[16]; };

#define THETA 10.0f

// ---------------- psp v7 (R13): 64 rows / 128 threads / 12.8 KB LDS ----------------
__global__ __launch_bounds__(128)
void psp_kernel(const float* __restrict__ in, float* __restrict__ out,
                int nrows, K32 pk) {
  __shared__ __align__(16) float lds[64 * 50];
  const int rowBase = blockIdx.x * 64;
  const int tid = threadIdx.x;
  const int vr = min(64, nrows - rowBase);   // always even here
  const int n4 = (vr * 50) >> 2;
  const float4* g4 = (const float4*)(in + (size_t)rowBase * 50);
  for (int i = tid; i < n4; i += 128) *(float4*)(&lds[4 * i]) = g4[i];
  __syncthreads();
  const int r = tid & 63;
  const int part = tid >> 6;
  const bool act = r < vr;
  float x[50];
  if (act) {
    if (part == 0) {
#pragma unroll
      for (int t = 0; t < 25; ++t) x[t] = lds[r * 50 + t];
    } else {
#pragma unroll
      for (int t = 0; t < 50; ++t) x[t] = lds[r * 50 + t];
    }
  }
  __syncthreads();
  if (act) {
    if (part == 0) {
#pragma unroll
      for (int t = 0; t < 25; ++t) {
        float a = 0.f;
#pragma unroll
        for (int k = 31; k >= 0; --k)          // x-index ascending (oldest first)
          if (t - k >= 0) a += x[t - k] * pk.k[k];
        lds[r * 50 + t] = a;
      }
    } else {
#pragma unroll
      for (int t = 25; t < 50; ++t) {
        float a = 0.f;
#pragma unroll
        for (int k = 31; k >= 0; --k)
          if (t - k >= 0) a += x[t - k] * pk.k[k];
        lds[r * 50 + t] = a;
      }
    }
  }
  __syncthreads();
  float4* o4 = (float4*)(out + (size_t)rowBase * 50);
  for (int i = tid; i < n4; i += 128) o4[i] = *(const float4*)(&lds[4 * i]);
}

// ====== fully fused stage 1 v2: psp1+conv1+spike1+psp2+pool1+spike2, SW=4 ======
// 30.8 KB LDS (5 blocks/CU), FIR patch 1 thread/row (no internal barrier),
// 7 barriers total. Per-row math identical to proven kernels.
template <int CIN, int COUT, int KK, int HIN, int WIN, int S1H, int S1W,
          int S2H, int S2W>
__global__ __launch_bounds__(256)
void conv_pps_kernel(const float* __restrict__ x, const float* __restrict__ w,
                     float* __restrict__ s2out, K32 pk, K16 rk) {
  constexpr int WT = 2;                       // s1-wo per wave
  constexpr int SW = 4;                       // s1-wo per block
  constexpr int XR = 2 * (WT - 1) + KK;       // 7
  constexpr int GROUPS = (S1W + SW - 1) / SW; // 32
  constexpr int NROW = COUT * 2 * SW;         // 64 spike rows
  constexpr int PH = KK + 2;                  // 7 patch h-rows
  constexpr int PW = 2 * (SW - 1) + KK;       // 11 patch cols
  constexpr int PR = CIN * PH * PW;           // 154 patch rows
  constexpr int LDSF = (PR * 50 > NROW * 51) ? PR * 50 : NROW * 51;
  __shared__ __align__(16) float lds[LDSF];   // 30.8 KB
  const int tid = threadIdx.x;
  const int wave = tid >> 6;
  const int lane = tid & 63;
  const int group = blockIdx.x % GROUPS;
  const int rest = blockIdx.x / GROUPS;
  const int hop = rest % S2H;                 // s2 ho
  const int n = rest / S2H;
  const int ho_off = wave & 1;
  const int wo_half = wave >> 1;              // 0 or 1
  const int tt = lane < 50 ? lane : 49;
  const int wi0 = 2 * group * SW - 1;         // patch col 0 -> this wi

  // ---- phase 1: stage raw-spike patch (14 contiguous spans, zero-fill pads) ----
  const float* xb = x + (size_t)n * CIN * HIN * WIN * 50;
#pragma unroll
  for (int sp = 0; sp < CIN * PH; ++sp) {
    const int c = sp / PH, ph = sp - c * PH;
    const int hi = 4 * hop - 1 + ph;
    const bool hok = (unsigned)hi < (unsigned)HIN;
    const float2* gp2 = (const float2*)(xb + (((long)c * HIN + hi) * (long)WIN + wi0) * 50);
    const int lo = (wi0 < 0) ? 25 : 0;
    const int hiE = (wi0 + PW > WIN) ? (WIN - wi0) * 25 : PW * 25;
    float* dst = &lds[sp * PW * 50];
    for (int e2 = tid; e2 < PW * 25; e2 += 256) {
      float2 v = make_float2(0.f, 0.f);
      if (hok && e2 >= lo && e2 < hiE) v = gp2[e2];
      *(float2*)(dst + 2 * e2) = v;
    }
  }
  __syncthreads();
  // ---- phase 2: FIR (psp1), 1 thread per patch row, own-row in-place ----
  if (tid < PR) {
    float xs[50];
#pragma unroll
    for (int t = 0; t < 50; ++t) xs[t] = lds[tid * 50 + t];
#pragma unroll
    for (int t = 0; t < 50; ++t) {
      float a = 0.f;
#pragma unroll
      for (int k = 31; k >= 0; --k)            // x-index ascending (oldest first)
        if (t - k >= 0) a += xs[t - k] * pk.k[k];
      lds[tid * 50 + t] = a;
    }
  }
  __syncthreads();
  // ---- phase 3: conv from LDS (order c -> kh -> co -> kw -> wl, unchanged) ----
  float acc[COUT][WT] = {};
#pragma unroll
  for (int c = 0; c < CIN; ++c) {
#pragma unroll
    for (int kh = 0; kh < KK; ++kh) {
      const int rowb = (c * PH + 2 * ho_off + kh) * PW + 2 * wo_half * WT;
      float xr[XR];
#pragma unroll
      for (int i = 0; i < XR; ++i) xr[i] = lds[(rowb + i) * 50 + tt];
#pragma unroll
      for (int co = 0; co < COUT; ++co)
#pragma unroll
        for (int kw = 0; kw < KK; ++kw) {
          const float wv = w[((co * CIN + c) * KK + kh) * KK + kw];
#pragma unroll
          for (int wl = 0; wl < WT; ++wl)
            acc[co][wl] += xr[2 * wl + kw] * wv;
        }
    }
  }
  __syncthreads();   // all waves done reading patch before transpose overwrites
  // ---- phase 4: transpose: LDS row = co*8 + ho_off*4 + wo_half*2 + wl ----
  if (lane < 50) {
#pragma unroll
    for (int co = 0; co < COUT; ++co)
#pragma unroll
      for (int wl = 0; wl < WT; ++wl)
        lds[((co * 2 + ho_off) * SW + wo_half * WT + wl) * 51 + lane] = acc[co][wl];
  }
  __syncthreads();
  // ---- phase 5: spike per s1 row (64 rows, in place) ----
  if (tid < NROW) {
    const int wol = tid & (SW - 1);
    if (group * SW + wol < S1W) {
      float buf[16];
#pragma unroll
      for (int j = 0; j < 16; ++j) buf[j] = 0.f;
#pragma unroll
      for (int t = 0; t < 50; ++t) {
        float v = lds[tid * 51 + t] + buf[t & 15];
        buf[t & 15] = 0.f;
        float sp = 0.f;
        if (v >= THETA) {
          sp = 1.f;
#pragma unroll
          for (int j = 0; j < 16; ++j) buf[(t + 1 + j) & 15] += rk.k[j];
        }
        lds[tid * 51 + t] = sp;
      }
    }
  }
  __syncthreads();
  // ---- phase 6: FIR (psp2) per s1 row: 2 threads/row (128 slots) ----
  {
    const int r = tid & (NROW - 1);
    const int part = (tid >> 6) & 1;
    const int wol = r & (SW - 1);
    const bool act = (tid < 2 * NROW) && (group * SW + wol < S1W);
    float xs[50];
    if (act) {
      if (part == 0) {
#pragma unroll
        for (int t = 0; t < 25; ++t) xs[t] = lds[r * 51 + t];
      } else {
#pragma unroll
        for (int t = 0; t < 50; ++t) xs[t] = lds[r * 51 + t];
      }
    }
    __syncthreads();
    if (act) {
      if (part == 0) {
#pragma unroll
        for (int t = 0; t < 25; ++t) {
          float a = 0.f;
#pragma unroll
          for (int k = 31; k >= 0; --k)
            if (t - k >= 0) a += xs[t - k] * pk.k[k];
          lds[r * 51 + t] = a;
        }
      } else {
#pragma unroll
        for (int t = 25; t < 50; ++t) {
          float a = 0.f;
#pragma unroll
          for (int k = 31; k >= 0; --k)
            if (t - k >= 0) a += xs[t - k] * pk.k[k];
          lds[r * 51 + t] = a;
        }
      }
    }
  }
  __syncthreads();
  // ---- phase 7: pool ((h0w0+h0w1)+h1w0)+h1w1 * 2.75 -> spike -> direct store ----
  if (tid < COUT * (SW / 2)) {                // 16 threads
    const int co = tid / (SW / 2);
    const int wpl = tid % (SW / 2);
    const int wop = group * (SW / 2) + wpl;   // s2 wo
    if (wop < S2W) {
      const int r00 = (co * 2 * SW + 2 * wpl) * 51;
      const int r01 = (co * 2 * SW + 2 * wpl + 1) * 51;
      const int r10 = (co * 2 * SW + SW + 2 * wpl) * 51;
      const int r11 = (co * 2 * SW + SW + 2 * wpl + 1) * 51;
      float* orow = s2out + (((size_t)(n * COUT + co) * S2H + hop) * S2W + wop) * 50;
      float buf[16];
#pragma unroll
      for (int j = 0; j < 16; ++j) buf[j] = 0.f;
      float prev = 0.f;
#pragma unroll
      for (int t = 0; t < 50; ++t) {
        const float u0 = (((lds[r00 + t] + lds[r01 + t]) + lds[r10 + t]) + lds[r11 + t]) * 2.75f;
        float v = u0 + buf[t & 15];
        buf[t & 15] = 0.f;
        float sp = 0.f;
        if (v >= THETA) {
          sp = 1.f;
#pragma unroll
          for (int j = 0; j < 16; ++j) buf[(t + 1 + j) & 15] += rk.k[j];
        }
        if (t & 1) *(float2*)(orow + t - 1) = make_float2(prev, sp);
        else prev = sp;
      }
    }
  }
}

// ---------------- fused conv (stride2,pad1) + spike, direct register store (R11-best) ----------------
template <int CIN, int COUT, int KK, int WT, int HIN, int WIN, int HOUT, int WOUT>
__global__ __launch_bounds__(256)
void conv_spike_kernel(const float* __restrict__ x, const float* __restrict__ w,
                       float* __restrict__ s, K16 rk) {
  constexpr int XR = 2 * (WT - 1) + KK;
  constexpr int TW = 4 * WT;                 // wo span per block (4 waves)
  constexpr int GROUPS = (WOUT + TW - 1) / TW;
  __shared__ float lds[COUT * TW * 51];
  const int tid = threadIdx.x;
  const int wave = tid >> 6;
  const int lane = tid & 63;
  const int group = blockIdx.x % GROUPS;
  const int rest = blockIdx.x / GROUPS;
  const int ho = rest % HOUT;
  const int n = rest / HOUT;
  const int wo0 = group * TW + wave * WT;
  const int tt = lane < 50 ? lane : 49;

  float acc[COUT][WT] = {};
  for (int c = 0; c < CIN; ++c) {
#pragma unroll
    for (int kh = 0; kh < KK; ++kh) {
      const int hi = 2 * ho + kh - 1;
      if ((unsigned)hi >= (unsigned)HIN) continue;   // zero padding
      float xr[XR];
#pragma unroll
      for (int i = 0; i < XR; ++i) {
        const int wi = 2 * wo0 - 1 + i;
        xr[i] = ((unsigned)wi < (unsigned)WIN)
                    ? x[(((size_t)(n * CIN + c) * HIN + hi) * WIN + wi) * 50 + tt]
                    : 0.f;
      }
#pragma unroll
      for (int co = 0; co < COUT; ++co)
#pragma unroll
        for (int kw = 0; kw < KK; ++kw) {
          const float wv = w[((co * CIN + c) * KK + kh) * KK + kw];
#pragma unroll
          for (int wl = 0; wl < WT; ++wl)
            acc[co][wl] += xr[2 * wl + kw] * wv;
        }
    }
  }

  if (lane < 50) {
#pragma unroll
    for (int co = 0; co < COUT; ++co)
#pragma unroll
      for (int wl = 0; wl < WT; ++wl)
        lds[(co * TW + wave * WT + wl) * 51 + lane] = acc[co][wl];
  }
  __syncthreads();
  // spike along t, one thread per output row, direct float2 store from regs
  if (tid < COUT * TW) {
    const int co = tid / TW;
    const int wol = tid - co * TW;
    const int wo = group * TW + wol;
    if (wo < WOUT) {
      float* orow = s + (((size_t)(n * COUT + co) * HOUT + ho) * WOUT + wo) * 50;
      float buf[16];
#pragma unroll
      for (int j = 0; j < 16; ++j) buf[j] = 0.f;
      float prev = 0.f;
#pragma unroll
      for (int t = 0; t < 50; ++t) {
        float v = lds[tid * 51 + t] + buf[t & 15];
        buf[t & 15] = 0.f;
        float sp = 0.f;
        if (v >= THETA) {
          sp = 1.f;
#pragma unroll
          for (int j = 0; j < 16; ++j) buf[(t + 1 + j) & 15] += rk.k[j];
        }
        if (t & 1) *(float2*)(orow + t - 1) = make_float2(prev, sp);
        else prev = sp;
      }
    }
  }
}

// ---------------- pps v5 (R10/R11-best): 128-thread blocks, 32-col segments ----------------
__global__ __launch_bounds__(128)
void pps_kernel(const float* __restrict__ in, float* __restrict__ out,
                int Hin, int Win, int Hout, int Wout, int nseg,
                K32 pk, K16 rk) {
  __shared__ __align__(16) float lds[80 * 50];   // 16 KB
  const int tid = threadIdx.x;
  const int seg = blockIdx.x % nseg;
  const int rest = blockIdx.x / nseg;
  const int ho = rest % Hout;
  const int nc = rest / Hout;
  const int wbase = seg * 32;                 // input col base
  const int nw = min(32, 2 * Wout - wbase);   // even
  const int nwo = nw >> 1;
  const int span = nw * 50;
  const float* b0 = in + ((size_t)(nc * Hin + 2 * ho) * Win + wbase) * 50;
  const float* b1 = b0 + (size_t)Win * 50;
  const int n2 = span >> 1;
  for (int i = tid; i < n2; i += 128) {
    *(float2*)(&lds[2 * i]) = *(const float2*)(b0 + 2 * i);
    *(float2*)(&lds[span + 2 * i]) = *(const float2*)(b1 + 2 * i);
  }
  __syncthreads();
  const int r = tid & 63;
  const int part = tid >> 6;
  const bool act = r < 2 * nw;
  float x[50];
  if (act) {
    if (part == 0) {
#pragma unroll
      for (int t = 0; t < 25; ++t) x[t] = lds[r * 50 + t];
    } else {
#pragma unroll
      for (int t = 0; t < 50; ++t) x[t] = lds[r * 50 + t];
    }
  }
  __syncthreads();
  if (act) {
    if (part == 0) {
#pragma unroll
      for (int t = 0; t < 25; ++t) {
        float a = 0.f;
#pragma unroll
        for (int k = 31; k >= 0; --k)
          if (t - k >= 0) a += x[t - k] * pk.k[k];
        lds[r * 50 + t] = a;
      }
    } else {
#pragma unroll
      for (int t = 25; t < 50; ++t) {
        float a = 0.f;
#pragma unroll
        for (int k = 31; k >= 0; --k)
          if (t - k >= 0) a += x[t - k] * pk.k[k];
        lds[r * 50 + t] = a;
      }
    }
  }
  __syncthreads();
  if (tid < nwo) {
    float buf[16];
#pragma unroll
    for (int j = 0; j < 16; ++j) buf[j] = 0.f;
    const int r00 = (2 * tid) * 50, r01 = (2 * tid + 1) * 50;
    const int r10 = (nw + 2 * tid) * 50, r11 = (nw + 2 * tid + 1) * 50;
    const int ro = (2 * nw + tid) * 50;
#pragma unroll
    for (int t = 0; t < 50; ++t) {
      const float u0 = (((lds[r00 + t] + lds[r01 + t]) + lds[r10 + t]) + lds[r11 + t]) * 2.75f;
      float v = u0 + buf[t & 15];
      buf[t & 15] = 0.f;
      float sp = 0.f;
      if (v >= THETA) {
        sp = 1.f;
#pragma unroll
        for (int j = 0; j < 16; ++j) buf[(t + 1 + j) & 15] += rk.k[j];
      }
      lds[ro + t] = sp;
    }
  }
  __syncthreads();
  float* ob = out + ((size_t)(nc * Hout + ho) * Wout + seg * 16) * 50;
  const int base = 2 * nw * 50;
  for (int i = tid; i < nwo * 25; i += 128)
    *(float2*)(ob + 2 * i) = *(const float2*)(&lds[base + 2 * i]);
}

// ---------------- fused fc + final spike ----------------
__global__ __launch_bounds__(512)
void fc_spike_kernel(const float* __restrict__ w, const float* __restrict__ u,
                     float* __restrict__ out, K16 rk) {
  __shared__ float lds[8 * 51];
  const int tid = threadIdx.x;
  const int wave = tid >> 6, lane = tid & 63;
  const int o = wave & 1, n = wave >> 1;
  const int tt = lane < 50 ? lane : 49;
  const float* wrow = w + (size_t)o * 2048;
  const float* ub = u + (size_t)n * 2048 * 50;
  float acc = 0.f;
#pragma unroll 32
  for (int i = 0; i < 2048; ++i) acc += wrow[i] * ub[(size_t)i * 50 + tt];
  if (lane < 50) lds[wave * 51 + lane] = acc;
  __syncthreads();
  if (tid < 8) {
    float buf[16];
#pragma unroll
    for (int j = 0; j < 16; ++j) buf[j] = 0.f;
#pragma unroll
    for (int t = 0; t < 50; ++t) {
      float v = lds[tid * 51 + t] + buf[t & 15];
      buf[t & 15] = 0.f;
      float sp = 0.f;
      if (v >= THETA) {
        sp = 1.f;
#pragma unroll
        for (int j = 0; j < 16; ++j) buf[(t + 1 + j) & 15] += rk.k[j];
      }
      out[tid * 50 + t] = sp;
    }
  }
}

extern "C" void kernel_launch(void* const* d_in, const int* in_sizes, int n_in,
                              void* d_out, int out_size, void* d_ws, size_t ws_size,
                              hipStream_t stream) {
  const float* xin = (const float*)d_in[0];  // [4,2,256,256,50] binary spikes
  const float* w1  = (const float*)d_in[1];  // [8,2,5,5]
  const float* w2  = (const float*)d_in[2];  // [16,8,3,3]
  const float* w3  = (const float*)d_in[3];  // [32,16,3,3]
  const float* wfc = (const float*)d_in[4];  // [2,32,8,8]
  float* out = (float*)d_out;                // [4,2,1,1,50]

  float* R0 = (float*)d_ws;                  // 26,214,400 floats
  float* R1 = R0 + 26214400;

  K32 pk;
  for (int k = 0; k < 32; ++k)
    pk.k[k] = (float)(((double)k / 10.0) * exp(1.0 - (double)k / 10.0));
  K16 rk;
  for (int j = 0; j < 16; ++j) {
    const double tr = (double)(j + 1);
    rk.k[j] = (float)(-2.0 * 10.0 * tr * exp(1.0 - tr));
  }

  // 1. FUSED psp1+conv1+spike1+psp2+pool1+spike2: xin -> R1 = s2 [4,8,63,63,50]
  //    SW=4 geometry: grid = 4 n * 63 s2-ho * 32 groups = 8064
  conv_pps_kernel<2, 8, 5, 256, 256, 127, 127, 63, 63>
      <<<4 * 63 * 32, 256, 0, stream>>>(xin, w1, R1, pk, rk);
  // 2. psp3: R1 -> R0 = u3 (127008 rows)
  psp_kernel<<<1985, 128, 0, stream>>>(R1, R0, 127008, pk);
  // 3. conv2+spike3: R0 -> R1 = s3 [4,16,32,32,50]; WT=1 -> GROUPS=8
  conv_spike_kernel<8, 16, 3, 1, 63, 63, 32, 32>
      <<<4 * 32 * 8, 256, 0, stream>>>(R0, w2, R1, rk);
  // 4. psp+pool+spike: R1 -> R0 = s4 [4,16,16,16,50]; nseg=1
  pps_kernel<<<4 * 16 * 16, 128, 0, stream>>>(R1, R0, 32, 32, 16, 16, 1, pk, rk);
  // 5. psp5: R0 -> R1 (16384 rows)
  psp_kernel<<<256, 128, 0, stream>>>(R0, R1, 16384, pk);
  // 6. conv3+spike5: R1 -> R0 = s5 [4,32,8,8,50]; GROUPS=2
  conv_spike_kernel<16, 32, 3, 1, 16, 16, 8, 8>
      <<<4 * 8 * 2, 256, 0, stream>>>(R1, w3, R0, rk);
  // 7. psp6: R0 -> R1 (8192 rows)
  psp_kernel<<<128, 128, 0, stream>>>(R0, R1, 8192, pk);
  // 8. fc + final spike -> out
  fc_spike_kernel<<<1, 512, 0, stream>>>(wfc, R1, out, rk);
}

// Round 17
// 505.283 us; speedup vs baseline: 1.6872x; 1.6872x over previous
//
#include <hip/hip_runtime.h>
#include <cmath>

struct K32 { float k[32]; };
struct K16 { float k[16]; };

#define THETA 10.0f

// ---------------- psp v7 (R13): 64 rows / 128 threads / 12.8 KB LDS ----------------
__global__ __launch_bounds__(128)
void psp_kernel(const float* __restrict__ in, float* __restrict__ out,
                int nrows, K32 pk) {
  __shared__ __align__(16) float lds[64 * 50];
  const int rowBase = blockIdx.x * 64;
  const int tid = threadIdx.x;
  const int vr = min(64, nrows - rowBase);   // always even here
  const int n4 = (vr * 50) >> 2;
  const float4* g4 = (const float4*)(in + (size_t)rowBase * 50);
  for (int i = tid; i < n4; i += 128) *(float4*)(&lds[4 * i]) = g4[i];
  __syncthreads();
  const int r = tid & 63;
  const int part = tid >> 6;
  const bool act = r < vr;
  float x[50];
  if (act) {
    if (part == 0) {
#pragma unroll
      for (int t = 0; t < 25; ++t) x[t] = lds[r * 50 + t];
    } else {
#pragma unroll
      for (int t = 0; t < 50; ++t) x[t] = lds[r * 50 + t];
    }
  }
  __syncthreads();
  if (act) {
    if (part == 0) {
#pragma unroll
      for (int t = 0; t < 25; ++t) {
        float a = 0.f;
#pragma unroll
        for (int k = 31; k >= 0; --k)          // x-index ascending (oldest first)
          if (t - k >= 0) a += x[t - k] * pk.k[k];
        lds[r * 50 + t] = a;
      }
    } else {
#pragma unroll
      for (int t = 25; t < 50; ++t) {
        float a = 0.f;
#pragma unroll
        for (int k = 31; k >= 0; --k)
          if (t - k >= 0) a += x[t - k] * pk.k[k];
        lds[r * 50 + t] = a;
      }
    }
  }
  __syncthreads();
  float4* o4 = (float4*)(out + (size_t)rowBase * 50);
  for (int i = tid; i < n4; i += 128) o4[i] = *(const float4*)(&lds[4 * i]);
}

// ====== fused conv(stride2,pad1)+spike + psp+pool(2x2,*2.75)+spike -> s2 (R14-best) ======
// Block: (n, s2-ho, group of 4 s2-wo) == (8co x 8 s1-wo x 2 s1-ho) = 128 LDS rows.
// Wave = (ho_off, wo_half), WT=4 -> acc[8][4] (proven). Phases sequential:
// conv(regs) -> transpose(LDS) -> spike/row -> FIR 2thr/row -> pool+spike+store.
template <int CIN, int COUT, int KK, int HIN, int WIN, int S1H, int S1W,
          int S2H, int S2W>
__global__ __launch_bounds__(256)
void conv_pps_kernel(const float* __restrict__ x, const float* __restrict__ w,
                     float* __restrict__ s2out, K32 pk, K16 rk) {
  constexpr int WT = 4;                       // s1-wo per wave
  constexpr int SW = 8;                       // s1-wo per block
  constexpr int XR = 2 * (WT - 1) + KK;       // 11
  constexpr int GROUPS = (S1W + SW - 1) / SW; // 16
  constexpr int NROW = COUT * 2 * SW;         // 128
  __shared__ float lds[NROW * 51];            // 26 KB
  const int tid = threadIdx.x;
  const int wave = tid >> 6;
  const int lane = tid & 63;
  const int group = blockIdx.x % GROUPS;
  const int rest = blockIdx.x / GROUPS;
  const int hop = rest % S2H;                 // s2 ho
  const int n = rest / S2H;
  const int ho_off = wave & 1;
  const int wo_half = wave >> 1;
  const int ho = 2 * hop + ho_off;            // s1 ho
  const int wo0 = group * SW + wo_half * WT;
  const int tt = lane < 50 ? lane : 49;

  // ---- conv (checked loads, proven order c -> kh -> co -> kw -> wl) ----
  float acc[COUT][WT] = {};
  for (int c = 0; c < CIN; ++c) {
#pragma unroll
    for (int kh = 0; kh < KK; ++kh) {
      const int hi = 2 * ho + kh - 1;
      if ((unsigned)hi >= (unsigned)HIN) continue;   // zero padding
      float xr[XR];
#pragma unroll
      for (int i = 0; i < XR; ++i) {
        const int wi = 2 * wo0 - 1 + i;
        xr[i] = ((unsigned)wi < (unsigned)WIN)
                    ? x[(((size_t)(n * CIN + c) * HIN + hi) * WIN + wi) * 50 + tt]
                    : 0.f;
      }
#pragma unroll
      for (int co = 0; co < COUT; ++co)
#pragma unroll
        for (int kw = 0; kw < KK; ++kw) {
          const float wv = w[((co * CIN + c) * KK + kh) * KK + kw];
#pragma unroll
          for (int wl = 0; wl < WT; ++wl)
            acc[co][wl] += xr[2 * wl + kw] * wv;
        }
    }
  }
  // ---- transpose: LDS row = co*16 + ho_off*8 + wol ----
  if (lane < 50) {
#pragma unroll
    for (int co = 0; co < COUT; ++co)
#pragma unroll
      for (int wl = 0; wl < WT; ++wl)
        lds[((co * 2 + ho_off) * SW + wo_half * WT + wl) * 51 + lane] = acc[co][wl];
  }
  __syncthreads();
  // ---- spike per s1 row (128 rows, in place) ----
  if (tid < NROW) {
    const int wol = tid & (SW - 1);
    if (group * SW + wol < S1W) {
      float buf[16];
#pragma unroll
      for (int j = 0; j < 16; ++j) buf[j] = 0.f;
#pragma unroll
      for (int t = 0; t < 50; ++t) {
        float v = lds[tid * 51 + t] + buf[t & 15];
        buf[t & 15] = 0.f;
        float sp = 0.f;
        if (v >= THETA) {
          sp = 1.f;
#pragma unroll
          for (int j = 0; j < 16; ++j) buf[(t + 1 + j) & 15] += rk.k[j];
        }
        lds[tid * 51 + t] = sp;
      }
    }
  }
  __syncthreads();
  // ---- FIR (psp2) per s1 row: 2 threads/row, snapshot -> barrier -> in-place ----
  {
    const int r = tid & (NROW - 1);
    const int part = tid >> 7;
    const int wol = r & (SW - 1);
    const bool act = (group * SW + wol) < S1W;
    float xs[50];
    if (act) {
      if (part == 0) {
#pragma unroll
        for (int t = 0; t < 25; ++t) xs[t] = lds[r * 51 + t];
      } else {
#pragma unroll
        for (int t = 0; t < 50; ++t) xs[t] = lds[r * 51 + t];
      }
    }
    __syncthreads();
    if (act) {
      if (part == 0) {
#pragma unroll
        for (int t = 0; t < 25; ++t) {
          float a = 0.f;
#pragma unroll
          for (int k = 31; k >= 0; --k)
            if (t - k >= 0) a += xs[t - k] * pk.k[k];
          lds[r * 51 + t] = a;
        }
      } else {
#pragma unroll
        for (int t = 25; t < 50; ++t) {
          float a = 0.f;
#pragma unroll
          for (int k = 31; k >= 0; --k)
            if (t - k >= 0) a += xs[t - k] * pk.k[k];
          lds[r * 51 + t] = a;
        }
      }
    }
  }
  __syncthreads();
  // ---- pool ((h0w0+h0w1)+h1w0)+h1w1 * 2.75 -> spike -> direct store ----
  if (tid < COUT * (SW / 2)) {                // 32 threads
    const int co = tid / (SW / 2);
    const int wpl = tid % (SW / 2);
    const int wop = group * (SW / 2) + wpl;   // s2 wo
    if (wop < S2W) {
      const int r00 = (co * 16 + 2 * wpl) * 51;
      const int r01 = (co * 16 + 2 * wpl + 1) * 51;
      const int r10 = (co * 16 + 8 + 2 * wpl) * 51;
      const int r11 = (co * 16 + 8 + 2 * wpl + 1) * 51;
      float* orow = s2out + (((size_t)(n * COUT + co) * S2H + hop) * S2W + wop) * 50;
      float buf[16];
#pragma unroll
      for (int j = 0; j < 16; ++j) buf[j] = 0.f;
      float prev = 0.f;
#pragma unroll
      for (int t = 0; t < 50; ++t) {
        const float u0 = (((lds[r00 + t] + lds[r01 + t]) + lds[r10 + t]) + lds[r11 + t]) * 2.75f;
        float v = u0 + buf[t & 15];
        buf[t & 15] = 0.f;
        float sp = 0.f;
        if (v >= THETA) {
          sp = 1.f;
#pragma unroll
          for (int j = 0; j < 16; ++j) buf[(t + 1 + j) & 15] += rk.k[j];
        }
        if (t & 1) *(float2*)(orow + t - 1) = make_float2(prev, sp);
        else prev = sp;
      }
    }
  }
}

// ---------------- fused conv (stride2,pad1) + spike, direct register store (R11-best) ----------------
template <int CIN, int COUT, int KK, int WT, int HIN, int WIN, int HOUT, int WOUT>
__global__ __launch_bounds__(256)
void conv_spike_kernel(const float* __restrict__ x, const float* __restrict__ w,
                       float* __restrict__ s, K16 rk) {
  constexpr int XR = 2 * (WT - 1) + KK;
  constexpr int TW = 4 * WT;                 // wo span per block (4 waves)
  constexpr int GROUPS = (WOUT + TW - 1) / TW;
  __shared__ float lds[COUT * TW * 51];
  const int tid = threadIdx.x;
  const int wave = tid >> 6;
  const int lane = tid & 63;
  const int group = blockIdx.x % GROUPS;
  const int rest = blockIdx.x / GROUPS;
  const int ho = rest % HOUT;
  const int n = rest / HOUT;
  const int wo0 = group * TW + wave * WT;
  const int tt = lane < 50 ? lane : 49;

  float acc[COUT][WT] = {};
  for (int c = 0; c < CIN; ++c) {
#pragma unroll
    for (int kh = 0; kh < KK; ++kh) {
      const int hi = 2 * ho + kh - 1;
      if ((unsigned)hi >= (unsigned)HIN) continue;   // zero padding
      float xr[XR];
#pragma unroll
      for (int i = 0; i < XR; ++i) {
        const int wi = 2 * wo0 - 1 + i;
        xr[i] = ((unsigned)wi < (unsigned)WIN)
                    ? x[(((size_t)(n * CIN + c) * HIN + hi) * WIN + wi) * 50 + tt]
                    : 0.f;
      }
#pragma unroll
      for (int co = 0; co < COUT; ++co)
#pragma unroll
        for (int kw = 0; kw < KK; ++kw) {
          const float wv = w[((co * CIN + c) * KK + kh) * KK + kw];
#pragma unroll
          for (int wl = 0; wl < WT; ++wl)
            acc[co][wl] += xr[2 * wl + kw] * wv;
        }
    }
  }

  if (lane < 50) {
#pragma unroll
    for (int co = 0; co < COUT; ++co)
#pragma unroll
      for (int wl = 0; wl < WT; ++wl)
        lds[(co * TW + wave * WT + wl) * 51 + lane] = acc[co][wl];
  }
  __syncthreads();
  // spike along t, one thread per output row, direct float2 store from regs
  if (tid < COUT * TW) {
    const int co = tid / TW;
    const int wol = tid - co * TW;
    const int wo = group * TW + wol;
    if (wo < WOUT) {
      float* orow = s + (((size_t)(n * COUT + co) * HOUT + ho) * WOUT + wo) * 50;
      float buf[16];
#pragma unroll
      for (int j = 0; j < 16; ++j) buf[j] = 0.f;
      float prev = 0.f;
#pragma unroll
      for (int t = 0; t < 50; ++t) {
        float v = lds[tid * 51 + t] + buf[t & 15];
        buf[t & 15] = 0.f;
        float sp = 0.f;
        if (v >= THETA) {
          sp = 1.f;
#pragma unroll
          for (int j = 0; j < 16; ++j) buf[(t + 1 + j) & 15] += rk.k[j];
        }
        if (t & 1) *(float2*)(orow + t - 1) = make_float2(prev, sp);
        else prev = sp;
      }
    }
  }
}

// ---------------- pps v5 (R10/R11-best): 128-thread blocks, 32-col segments ----------------
__global__ __launch_bounds__(128)
void pps_kernel(const float* __restrict__ in, float* __restrict__ out,
                int Hin, int Win, int Hout, int Wout, int nseg,
                K32 pk, K16 rk) {
  __shared__ __align__(16) float lds[80 * 50];   // 16 KB
  const int tid = threadIdx.x;
  const int seg = blockIdx.x % nseg;
  const int rest = blockIdx.x / nseg;
  const int ho = rest % Hout;
  const int nc = rest / Hout;
  const int wbase = seg * 32;                 // input col base
  const int nw = min(32, 2 * Wout - wbase);   // even
  const int nwo = nw >> 1;
  const int span = nw * 50;
  const float* b0 = in + ((size_t)(nc * Hin + 2 * ho) * Win + wbase) * 50;
  const float* b1 = b0 + (size_t)Win * 50;
  const int n2 = span >> 1;
  for (int i = tid; i < n2; i += 128) {
    *(float2*)(&lds[2 * i]) = *(const float2*)(b0 + 2 * i);
    *(float2*)(&lds[span + 2 * i]) = *(const float2*)(b1 + 2 * i);
  }
  __syncthreads();
  const int r = tid & 63;
  const int part = tid >> 6;
  const bool act = r < 2 * nw;
  float x[50];
  if (act) {
    if (part == 0) {
#pragma unroll
      for (int t = 0; t < 25; ++t) x[t] = lds[r * 50 + t];
    } else {
#pragma unroll
      for (int t = 0; t < 50; ++t) x[t] = lds[r * 50 + t];
    }
  }
  __syncthreads();
  if (act) {
    if (part == 0) {
#pragma unroll
      for (int t = 0; t < 25; ++t) {
        float a = 0.f;
#pragma unroll
        for (int k = 31; k >= 0; --k)
          if (t - k >= 0) a += x[t - k] * pk.k[k];
        lds[r * 50 + t] = a;
      }
    } else {
#pragma unroll
      for (int t = 25; t < 50; ++t) {
        float a = 0.f;
#pragma unroll
        for (int k = 31; k >= 0; --k)
          if (t - k >= 0) a += x[t - k] * pk.k[k];
        lds[r * 50 + t] = a;
      }
    }
  }
  __syncthreads();
  if (tid < nwo) {
    float buf[16];
#pragma unroll
    for (int j = 0; j < 16; ++j) buf[j] = 0.f;
    const int r00 = (2 * tid) * 50, r01 = (2 * tid + 1) * 50;
    const int r10 = (nw + 2 * tid) * 50, r11 = (nw + 2 * tid + 1) * 50;
    const int ro = (2 * nw + tid) * 50;
#pragma unroll
    for (int t = 0; t < 50; ++t) {
      const float u0 = (((lds[r00 + t] + lds[r01 + t]) + lds[r10 + t]) + lds[r11 + t]) * 2.75f;
      float v = u0 + buf[t & 15];
      buf[t & 15] = 0.f;
      float sp = 0.f;
      if (v >= THETA) {
        sp = 1.f;
#pragma unroll
        for (int j = 0; j < 16; ++j) buf[(t + 1 + j) & 15] += rk.k[j];
      }
      lds[ro + t] = sp;
    }
  }
  __syncthreads();
  float* ob = out + ((size_t)(nc * Hout + ho) * Wout + seg * 16) * 50;
  const int base = 2 * nw * 50;
  for (int i = tid; i < nwo * 25; i += 128)
    *(float2*)(ob + 2 * i) = *(const float2*)(&lds[base + 2 * i]);
}

// ---------------- fused fc + final spike ----------------
__global__ __launch_bounds__(512)
void fc_spike_kernel(const float* __restrict__ w, const float* __restrict__ u,
                     float* __restrict__ out, K16 rk) {
  __shared__ float lds[8 * 51];
  const int tid = threadIdx.x;
  const int wave = tid >> 6, lane = tid & 63;
  const int o = wave & 1, n = wave >> 1;
  const int tt = lane < 50 ? lane : 49;
  const float* wrow = w + (size_t)o * 2048;
  const float* ub = u + (size_t)n * 2048 * 50;
  float acc = 0.f;
#pragma unroll 32
  for (int i = 0; i < 2048; ++i) acc += wrow[i] * ub[(size_t)i * 50 + tt];
  if (lane < 50) lds[wave * 51 + lane] = acc;
  __syncthreads();
  if (tid < 8) {
    float buf[16];
#pragma unroll
    for (int j = 0; j < 16; ++j) buf[j] = 0.f;
#pragma unroll
    for (int t = 0; t < 50; ++t) {
      float v = lds[tid * 51 + t] + buf[t & 15];
      buf[t & 15] = 0.f;
      float sp = 0.f;
      if (v >= THETA) {
        sp = 1.f;
#pragma unroll
        for (int j = 0; j < 16; ++j) buf[(t + 1 + j) & 15] += rk.k[j];
      }
      out[tid * 50 + t] = sp;
    }
  }
}

extern "C" void kernel_launch(void* const* d_in, const int* in_sizes, int n_in,
                              void* d_out, int out_size, void* d_ws, size_t ws_size,
                              hipStream_t stream) {
  const float* xin = (const float*)d_in[0];  // [4,2,256,256,50]
  const float* w1  = (const float*)d_in[1];  // [8,2,5,5]
  const float* w2  = (const float*)d_in[2];  // [16,8,3,3]
  const float* w3  = (const float*)d_in[3];  // [32,16,3,3]
  const float* wfc = (const float*)d_in[4];  // [2,32,8,8]
  float* out = (float*)d_out;                // [4,2,1,1,50]

  float* R0 = (float*)d_ws;                  // 26,214,400 floats
  float* R1 = R0 + 26214400;

  K32 pk;
  for (int k = 0; k < 32; ++k)
    pk.k[k] = (float)(((double)k / 10.0) * exp(1.0 - (double)k / 10.0));
  K16 rk;
  for (int j = 0; j < 16; ++j) {
    const double tr = (double)(j + 1);
    rk.k[j] = (float)(-2.0 * 10.0 * tr * exp(1.0 - tr));
  }

  // 1. psp1: xin -> R0 = u1 (524288 rows)
  psp_kernel<<<8192, 128, 0, stream>>>(xin, R0, 524288, pk);
  // 2. FUSED conv1+spike1+psp2+pool1+spike2: R0 -> R1 = s2 [4,8,63,63,50]
  //    grid = 4 n * 63 s2-ho * 16 groups = 4032
  conv_pps_kernel<2, 8, 5, 256, 256, 127, 127, 63, 63>
      <<<4 * 63 * 16, 256, 0, stream>>>(R0, w1, R1, pk, rk);
  // 3. psp3: R1 -> R0 = u3 (127008 rows)
  psp_kernel<<<1985, 128, 0, stream>>>(R1, R0, 127008, pk);
  // 4. conv2+spike3: R0 -> R1 = s3 [4,16,32,32,50]; WT=1 -> GROUPS=8
  conv_spike_kernel<8, 16, 3, 1, 63, 63, 32, 32>
      <<<4 * 32 * 8, 256, 0, stream>>>(R0, w2, R1, rk);
  // 5. psp+pool+spike: R1 -> R0 = s4 [4,16,16,16,50]; nseg=1
  pps_kernel<<<4 * 16 * 16, 128, 0, stream>>>(R1, R0, 32, 32, 16, 16, 1, pk, rk);
  // 6. psp5: R0 -> R1 (16384 rows)
  psp_kernel<<<256, 128, 0, stream>>>(R0, R1, 16384, pk);
  // 7. conv3+spike5: R1 -> R0 = s5 [4,32,8,8,50]; GROUPS=2
  conv_spike_kernel<16, 32, 3, 1, 16, 16, 8, 8>
      <<<4 * 8 * 2, 256, 0, stream>>>(R1, w3, R0, rk);
  // 8. psp6: R0 -> R1 (8192 rows)
  psp_kernel<<<128, 128, 0, stream>>>(R0, R1, 8192, pk);
  // 9. fc + final spike -> out
  fc_spike_kernel<<<1, 512, 0, stream>>>(wfc, R1, out, rk);
}